// Round 3
// baseline (2039.579 us; speedup 1.0000x reference)
//
#include <hip/hip_runtime.h>

// ============================================================================
// GeneratorBilinear: fused PGA(3,0,1) bilinear block on MI355X (gfx950).
// Round 3: fp32 inputs AND fp32 output (per reference dtypes).
//
//   h  = equi_linear(x, w_bili)          [B,P,96,16]
//   gp = geometric_product(h[0:24], h[24:48])
//   jn = equi_join(h[48:72], h[72:96], ref)  (= undual(wedge(dual,dual))*ref_ps)
//   out= equi_linear([gp;jn], w_next)    [B,P,48,16]  -> fp32
//
// equi_linear decomposition (verified against reference basis construction):
//   out[o,k] = sum_i w[o,i,grade(k)] * x[i,k]
//            + (e0 in k) * sum_i w[o,i,4+grade(k)] * x[i, k\e0]
// (all e0-multiplication basis signs are +1: prepending e0 needs no swaps)
// ============================================================================

typedef unsigned short ushort_t;
typedef unsigned int uint_t;

// ---------------- compile-time PGA tables (mirror reference _mul) -----------
constexpr unsigned char BB[16] = {
  0x0, 0x1, 0x2, 0x4, 0x8,            // (), e0, e1, e2, e3
  0x3, 0x5, 0x9, 0x6, 0xA, 0xC,       // e01,e02,e03,e12,e13,e23
  0x7, 0xB, 0xD, 0xE,                 // e012,e013,e023,e123
  0xF                                 // e0123
};
constexpr int popc4(unsigned x){ return (x&1)+((x>>1)&1)+((x>>2)&1)+((x>>3)&1); }
constexpr int idx_of(unsigned bits){
  int r = 0;
  for (int i = 0; i < 16; ++i) if (BB[i] == bits) r = i;
  return r;
}
// sign from bubble-sorting concat(a,b): (-1)^(# inversions between a and b)
constexpr int reorder_sign(unsigned a, unsigned b){
  int sw = 0;
  for (int g = 0; g < 4; ++g) if (b & (1u<<g)) sw += popc4(a >> (g+1));
  return (sw & 1) ? -1 : 1;
}
struct Tab { signed char s[16][16]; signed char k[16][16]; };
constexpr Tab make_gp(){
  Tab t{};
  for (int i = 0; i < 16; ++i)
    for (int j = 0; j < 16; ++j){
      unsigned a = BB[i], b = BB[j];
      if ((a & b) & 1u) { t.s[i][j] = 0; t.k[i][j] = 0; }    // e0^2 = 0
      else { t.s[i][j] = (signed char)reorder_sign(a,b);      // e1..e3 square +1
             t.k[i][j] = (signed char)idx_of(a ^ b); }
    }
  return t;
}
constexpr int d_idx(int i){ return idx_of(0xFu ^ BB[i]); }
constexpr int d_sgn(int i){ return reorder_sign(BB[i], 0xFu ^ BB[i]); }
// fused join table: undual(wedge(dual(x),dual(y)))  -> j[l] = sum s*x[a]*y[b]
constexpr Tab make_join(){
  Tab t{};
  for (int a = 0; a < 16; ++a)
    for (int b = 0; b < 16; ++b){
      int da = d_idx(a), db = d_idx(b);
      if (BB[da] & BB[db]) { t.s[a][b] = 0; t.k[a][b] = 0; }
      else {
        int ws = reorder_sign(BB[da], BB[db]);
        int m  = idx_of(BB[da] ^ BB[db]);       // wedge result blade
        int l  = idx_of(0xFu ^ BB[m]);          // undual: comp(l) == m
        t.s[a][b] = (signed char)(d_sgn(a) * d_sgn(b) * ws * d_sgn(l));
        t.k[a][b] = (signed char)l;
      }
    }
  return t;
}
constexpr Tab GPT = make_gp();
constexpr Tab JNT = make_join();

struct ITab { int v[16]; };
constexpr ITab make_grade(){ ITab t{}; for (int i=0;i<16;++i) t.v[i]=popc4(BB[i]); return t; }
constexpr ITab make_partner(){ ITab t{}; for (int i=0;i<16;++i) t.v[i]=idx_of(BB[i] & ~1u); return t; }
constexpr ITab GRD = make_grade();
constexpr ITab PRT = make_partner();
// wave grouping: slots 0..7 = e0-free blades (waves 0,1), slots 8..15 = e0 blades (waves 2,3)
constexpr int KPERM[16] = {0,2,3,4,8,9,10,14,  1,5,6,7,11,12,13,15};

// ---------------- sizes ------------------------------------------------------
#define NPTS   65536          // B*P = 64*1024
#define CIN    48
#define CH     96             // 2*C_inter
#define COUT   48
#define PTS    16             // points per block
#define XROWF  772            // fp32 elems/point in x tile (768 data + 4 pad)
#define GSTR   272            // fp32 elems per g-channel row: [c][17p+k]
#define BUF_F  13056          // overlay buffer floats: max(16*772=12352, 48*272=13056)
#define HROW   1540           // fp32 elems/point in h tile (1536 data + 4 pad)
#define OROWF  772            // fp32 elems/point in output staging (768 + 4 pad)

// ---------------- weight prep: fp32 [o][i][9] -> fp32 [9][o][i] -------------
__global__ void prep_weights(const float* __restrict__ wb,
                             const float* __restrict__ wn,
                             float* __restrict__ W1, float* __restrict__ W2){
  int i = blockIdx.x * 256 + threadIdx.x;
  if (i < 9*CH*CIN){
    int b = i / (CH*CIN); int r = i % (CH*CIN); int o = r / CIN; int c = r % CIN;
    W1[i] = wb[(o*CIN + c)*9 + b];
  }
  if (i < 9*COUT*CIN){
    int b = i / (COUT*CIN); int r = i % (COUT*CIN); int o = r / CIN; int c = r % CIN;
    W2[i] = wn[(o*CIN + c)*9 + b];
  }
}

// ---------------- fused main kernel ------------------------------------------
__global__ __launch_bounds__(256, 1)
void fused_bilinear(const float* __restrict__ x,     // [NPTS][48][16] fp32
                    const float* __restrict__ refp,  // [64][16] fp32
                    const float* __restrict__ W1,    // [9][96][48] fp32
                    const float* __restrict__ W2,    // [9][48][48] fp32
                    float* __restrict__ out){        // [NPTS][48][16] fp32
  __shared__ float buf[BUF_F];          // xs (stage 0/1) overlaid with gs (2/3): 52,224 B
  __shared__ float hs[PTS * HROW];      // 98,560 B     (total 150,784 B)

  const int t  = threadIdx.x;
  const long p0 = (long)blockIdx.x * PTS;

  // ---- stage 0: coalesced fp32 x tile load (float4 per thread per chunk) ----
  for (int c = t; c < PTS * 192; c += 256){            // 192 float4-chunks per point
    int p = c / 192, r = c % 192;
    float4 v = ((const float4*)(x + (p0 + p) * 768))[r];
    ((float4*)(buf + p * XROWF))[r] = v;
  }
  __syncthreads();

  // ---- stage 1: h = equi_linear(x, w_bili), fp32 ----
  {
    const int p = t & 15, slot = t >> 4;
    const int k  = KPERM[slot];
    const int b0 = GRD.v[k];
    const int kp = PRT.v[k];
    const bool has_e0 = (BB[k] & 1u) != 0;
    const float* w0 = W1 + b0 * (CH*CIN);
    const float* w1 = W1 + (4 + b0) * (CH*CIN);

    float xr[CIN];
    #pragma unroll
    for (int i = 0; i < CIN; ++i) xr[i] = buf[p*XROWF + i*16 + k];

    if (!has_e0){
      #pragma unroll 2
      for (int o = 0; o < CH; ++o){
        const float* wr = w0 + o * CIN;
        float a0=0.f,a1=0.f,a2=0.f,a3=0.f;
        #pragma unroll
        for (int i = 0; i < CIN; i += 4){
          a0 += wr[i]*xr[i];     a1 += wr[i+1]*xr[i+1];
          a2 += wr[i+2]*xr[i+2]; a3 += wr[i+3]*xr[i+3];
        }
        hs[p*HROW + o*16 + k] = (a0+a1)+(a2+a3);
      }
    } else {
      float xr2[CIN];
      #pragma unroll
      for (int i = 0; i < CIN; ++i) xr2[i] = buf[p*XROWF + i*16 + kp];
      #pragma unroll 2
      for (int o = 0; o < CH; ++o){
        const float* wr  = w0 + o * CIN;
        const float* wr2 = w1 + o * CIN;
        float a0=0.f,a1=0.f,a2=0.f,a3=0.f;
        #pragma unroll
        for (int i = 0; i < CIN; i += 4){
          a0 += wr[i]*xr[i];       a1 += wr[i+1]*xr[i+1];
          a2 += wr[i+2]*xr[i+2];   a3 += wr[i+3]*xr[i+3];
          a0 += wr2[i]*xr2[i];     a1 += wr2[i+1]*xr2[i+1];
          a2 += wr2[i+2]*xr2[i+2]; a3 += wr2[i+3]*xr2[i+3];
        }
        hs[p*HROW + o*16 + k] = (a0+a1)+(a2+a3);
      }
    }
  }
  __syncthreads();   // also protects buf reuse: xs reads done, gs writes follow

  // ---- stage 2: gp / join bilinears (768 tasks = 16 pts x 48 channels) ----
  for (int tau = t; tau < 768; tau += 256){
    const int p = tau & 15, u = tau >> 4;      // u<24: gp channel u; else join u-24
    if (u < 24){
      float lg[16], rg[16], oo[16];
      #pragma unroll
      for (int k = 0; k < 16; ++k){
        lg[k] = hs[p*HROW + u*16 + k];
        rg[k] = hs[p*HROW + (24+u)*16 + k];
        oo[k] = 0.f;
      }
      #pragma unroll
      for (int i = 0; i < 16; ++i)
        #pragma unroll
        for (int j = 0; j < 16; ++j){
          const int s = GPT.s[i][j];
          if (s > 0)      oo[GPT.k[i][j]] += lg[i]*rg[j];
          else if (s < 0) oo[GPT.k[i][j]] -= lg[i]*rg[j];
        }
      #pragma unroll
      for (int k = 0; k < 16; ++k) buf[u*GSTR + p*17 + k] = oo[k];
    } else {
      const int c = u - 24;
      float lj[16], rj[16], oo[16];
      #pragma unroll
      for (int k = 0; k < 16; ++k){
        lj[k] = hs[p*HROW + (48+c)*16 + k];
        rj[k] = hs[p*HROW + (72+c)*16 + k];
        oo[k] = 0.f;
      }
      #pragma unroll
      for (int i = 0; i < 16; ++i)
        #pragma unroll
        for (int j = 0; j < 16; ++j){
          const int s = JNT.s[i][j];
          if (s > 0)      oo[JNT.k[i][j]] += lj[i]*rj[j];
          else if (s < 0) oo[JNT.k[i][j]] -= lj[i]*rj[j];
        }
      const float rps = refp[(int)((p0 + p) >> 10) * 16 + 15];
      #pragma unroll
      for (int k = 0; k < 16; ++k) buf[u*GSTR + p*17 + k] = oo[k]*rps;
    }
  }
  __syncthreads();

  // ---- stage 3: out = equi_linear(g, w_next); stage fp32 into LDS (hs reuse) ----
  float* outS = hs;   // [PTS][OROWF] fp32 staging; hs dead after stage 2
  {
    const int p = t & 15, slot = t >> 4;
    const int k  = KPERM[slot];
    const int b0 = GRD.v[k];
    const int kp = PRT.v[k];
    const bool has_e0 = (BB[k] & 1u) != 0;
    const float* w0 = W2 + b0 * (COUT*CIN);
    const float* w1 = W2 + (4 + b0) * (COUT*CIN);

    float gr[CIN];
    #pragma unroll
    for (int c = 0; c < CIN; ++c) gr[c] = buf[c*GSTR + p*17 + k];

    if (!has_e0){
      #pragma unroll 2
      for (int o = 0; o < COUT; ++o){
        const float* wr = w0 + o * CIN;
        float a0=0.f,a1=0.f,a2=0.f,a3=0.f;
        #pragma unroll
        for (int c = 0; c < CIN; c += 4){
          a0 += wr[c]*gr[c];     a1 += wr[c+1]*gr[c+1];
          a2 += wr[c+2]*gr[c+2]; a3 += wr[c+3]*gr[c+3];
        }
        outS[p*OROWF + o*16 + k] = (a0+a1)+(a2+a3);
      }
    } else {
      float gr2[CIN];
      #pragma unroll
      for (int c = 0; c < CIN; ++c) gr2[c] = buf[c*GSTR + p*17 + kp];
      #pragma unroll 2
      for (int o = 0; o < COUT; ++o){
        const float* wr  = w0 + o * CIN;
        const float* wr2 = w1 + o * CIN;
        float a0=0.f,a1=0.f,a2=0.f,a3=0.f;
        #pragma unroll
        for (int c = 0; c < CIN; c += 4){
          a0 += wr[c]*gr[c];       a1 += wr[c+1]*gr[c+1];
          a2 += wr[c+2]*gr[c+2];   a3 += wr[c+3]*gr[c+3];
          a0 += wr2[c]*gr2[c];     a1 += wr2[c+1]*gr2[c+1];
          a2 += wr2[c+2]*gr2[c+2]; a3 += wr2[c+3]*gr2[c+3];
        }
        outS[p*OROWF + o*16 + k] = (a0+a1)+(a2+a3);
      }
    }
  }
  __syncthreads();

  // ---- stage 4: coalesced fp32 store (float4 = dwordx4) ----
  for (int c = t; c < PTS * 192; c += 256){            // 192 float4-chunks per point
    int p = c / 192, r = c % 192;
    float4 v = ((const float4*)(outS + p * OROWF))[r];
    ((float4*)(out + (p0 + p) * 768))[r] = v;
  }
}

// ---------------- launch -----------------------------------------------------
extern "C" void kernel_launch(void* const* d_in, const int* in_sizes, int n_in,
                              void* d_out, int out_size, void* d_ws, size_t ws_size,
                              hipStream_t stream){
  (void)in_sizes; (void)n_in; (void)out_size; (void)ws_size;
  const float* hidden = (const float*)d_in[0];   // [64,1024,48,16] fp32
  const float* refp   = (const float*)d_in[1];   // [64,1,1,16]     fp32
  const float* wbili  = (const float*)d_in[2];   // [96,48,9]       fp32
  const float* wnext  = (const float*)d_in[3];   // [48,48,9]       fp32
  float* outp = (float*)d_out;                   // [64,1024,48,16] fp32

  float* W1 = (float*)d_ws;                 // [9][96][48] fp32 = 165,888 B
  float* W2 = W1 + 9*CH*CIN;                // [9][48][48] fp32 =  82,944 B

  prep_weights<<<162, 256, 0, stream>>>(wbili, wnext, W1, W2);
  fused_bilinear<<<NPTS/PTS, 256, 0, stream>>>(hidden, refp, W1, W2, outp);
}